// Round 8
// baseline (328.606 us; speedup 1.0000x reference)
//
#include <hip/hip_runtime.h>
#include <hip/hip_cooperative_groups.h>

namespace cg = cooperative_groups;

// Problem constants (fixed by setup_inputs)
#define B_    16
#define N_    262144            // 2^18 pixels per image
#define NC    150               // classes
#define NP    4096              // pred segment ids
#define T_    (B_ * NC)         // 2400 distinct target ids
#define TOTAL (B_ * N_)         // 4,194,304 pixels

// partition: 256 parent buckets (pred>>4)
#define PBKT       256
#define PCAP       18432        // mean 16384, +16 sigma
#define KEY_SHIFT  16           // local key = (p&15)*2400 + t < 38400 < 2^16
#define GRID       1024
#define P1_PIX     (TOTAL / GRID)        // 4096 pixels per block (one image)
#define P1_PER_THR (P1_PIX / 256)        // 16 per thread

// iou phase: 4 co-blocks per parent bucket, each owns 4 pred rows
#define QT         9600         // local keys per quadrant (4*2400)

#define NCOUNTERS  (PBKT + T_)  // 2656 u32 (gCount then gNT, contiguous)

// Shared-memory arena byte offsets (phases overlay the same LDS)
// phase 1 (partition): 20.6 KB
#define OFF_CNT     0           // 256 u32
#define OFF_LSTART  1024        // 256 u32
#define OFF_GOFF    2048        // 256 u32
#define OFF_CURSOR  3072        // 256 u32
#define OFF_NTH     4096        // 150 u32
#define OFF_STAGING 4704        // 4096 u32 (16 KB)
// phase 2 (iou): 25.7 KB
#define OFF_HIST    0           // 4800 u32 (19.2 KB)
#define OFF_NPRED   19200       // 4 f32
#define OFF_IOUPC   19216       // 600 f32
#define OFF_RED4    21616       // 256 float4 (16B-aligned)
#define SH_BYTES    25712

typedef unsigned int u32;
typedef unsigned short u16;

// ---------------------------------------------------------------------------
// One cooperative kernel: init -> grid.sync -> partition -> grid.sync -> iou
// ---------------------------------------------------------------------------
__global__ __launch_bounds__(256) void fused_kernel(
        const int* __restrict__ pred, const int* __restrict__ tgt,
        u16* __restrict__ records, u32* __restrict__ gCount,
        u32* __restrict__ gNT, const float* __restrict__ targets,
        float* __restrict__ out) {
    __shared__ __align__(16) char shraw[SH_BYTES];
    cg::grid_group grid = cg::this_grid();
    int tid = threadIdx.x;
    int blk = blockIdx.x;

    // ---- phase 0: zero the counters (gCount & gNT contiguous in d_ws) ----
    {
        int i = blk * 256 + tid;
        if (i < NCOUNTERS) gCount[i] = 0;
    }
    grid.sync();

    // ---- phase 1: radix-split into 256 parent buckets (+ fused n_tgt) ----
    {
        u32* cnt     = (u32*)(shraw + OFF_CNT);
        u32* lstart  = (u32*)(shraw + OFF_LSTART);
        u32* goff    = (u32*)(shraw + OFF_GOFF);
        u32* cursor  = (u32*)(shraw + OFF_CURSOR);
        u32* nth     = (u32*)(shraw + OFF_NTH);
        u32* staging = (u32*)(shraw + OFF_STAGING);

        cnt[tid] = 0;
        if (tid < NC) nth[tid] = 0;
        __syncthreads();

        u32 keys[P1_PER_THR];
        int base = blk * P1_PIX;
        int b_img = base >> 18;                  // constant per block
        const int4* pred4 = (const int4*)pred;
        const int4* tgt4  = (const int4*)tgt;

        #pragma unroll
        for (int k = 0; k < P1_PER_THR / 4; ++k) {
            int vi = (base >> 2) + k * 256 + tid;
            int4 pv = pred4[vi];
            int4 tv = tgt4[vi];
            int pe[4] = {pv.x, pv.y, pv.z, pv.w};
            int te[4] = {tv.x, tv.y, tv.z, tv.w};
            #pragma unroll
            for (int e = 0; e < 4; ++e) {
                int p = pe[e];
                u32 bkt = (u32)(p >> 4);
                u32 lk  = (u32)((p & 15) * T_ + b_img * NC + te[e]);
                keys[k * 4 + e] = (bkt << KEY_SHIFT) | lk;
                atomicAdd(&cnt[bkt], 1u);
                atomicAdd(&nth[te[e]], 1u);
            }
        }
        __syncthreads();

        // exclusive prefix over 256 bucket counts (Hillis-Steele)
        lstart[tid] = cnt[tid];
        __syncthreads();
        for (int off = 1; off < PBKT; off <<= 1) {
            u32 v = 0;
            if (tid >= off) v = lstart[tid - off];
            __syncthreads();
            if (tid >= off) lstart[tid] += v;
            __syncthreads();
        }
        {
            u32 ex = lstart[tid] - cnt[tid];
            lstart[tid] = ex;
            cursor[tid] = ex;
            u32 gb = atomicAdd(&gCount[tid], cnt[tid]);
            goff[tid] = gb - ex;
        }
        if (tid < NC && nth[tid]) atomicAdd(&gNT[b_img * NC + tid], nth[tid]);
        __syncthreads();

        // scatter into LDS staging, sorted by bucket
        #pragma unroll
        for (int k = 0; k < P1_PER_THR; ++k) {
            u32 v = keys[k];
            u32 pos = atomicAdd(&cursor[v >> KEY_SHIFT], 1u);
            staging[pos] = v;
        }
        __syncthreads();

        // coalesced flush: ~16-record (32 B) runs per bucket
        for (int r = tid; r < P1_PIX; r += 256) {
            u32 v = staging[r];
            u32 bkt = v >> KEY_SHIFT;
            u32 gp = goff[bkt] + (u32)r;         // = gbase + (r - lstart)
            if (gp < PCAP) records[(size_t)bkt * PCAP + gp] = (u16)(v & 0xFFFFu);
        }
    }
    __threadfence();
    grid.sync();

    // ---- phase 2: iou. Block blk -> bucket blk>>2, quadrant blk&3 ----
    {
        u32*   hist    = (u32*)(shraw + OFF_HIST);
        float* npred_s = (float*)(shraw + OFF_NPRED);
        float (*iou_pc)[NC] = (float(*)[NC])(shraw + OFF_IOUPC);
        float4* red4   = (float4*)(shraw + OFF_RED4);

        int bkt = blk >> 2;
        int q   = blk & 3;
        u32 lo = (u32)(q * QT);

        // vectorized hist zero
        {
            uint4 z4 = make_uint4(0u, 0u, 0u, 0u);
            uint4* h4 = (uint4*)hist;
            for (int j = tid; j < QT / 8; j += 256) h4[j] = z4;
        }
        __syncthreads();

        u32 cnt = gCount[bkt];
        if (cnt > PCAP) cnt = PCAP;
        const u16* rec = records + (size_t)bkt * PCAP;

        // vectorized scan (8 B/lane), single-compare filter to this quadrant
        u32 nv4 = cnt >> 2;
        const ushort4* rec4 = (const ushort4*)rec;
        for (u32 r = tid; r < nv4; r += 256) {
            ushort4 v4 = rec4[r];
            u32 e[4] = {v4.x, v4.y, v4.z, v4.w};
            #pragma unroll
            for (int i = 0; i < 4; ++i) {
                u32 lk = e[i] - lo;
                if (lk < (u32)QT)
                    atomicAdd(&hist[lk >> 1], (lk & 1u) ? 65536u : 1u);
            }
        }
        for (u32 r = (nv4 << 2) + tid; r < cnt; r += 256) {
            u32 lk = (u32)rec[r] - lo;
            if (lk < (u32)QT)
                atomicAdd(&hist[lk >> 1], (lk & 1u) ? 65536u : 1u);
        }
        __syncthreads();

        // n_pred row sums: 4 waves, one pred row each (1200 words)
        {
            int pl = tid >> 6, lane = tid & 63;
            u32 s = 0;
            for (int w = lane; w < T_ / 2; w += 64) {
                u32 v = hist[pl * (T_ / 2) + w];
                s += (v & 0xFFFFu) + (v >> 16);
            }
            #pragma unroll
            for (int o = 32; o > 0; o >>= 1) s += __shfl_xor(s, o);
            if (lane == 0) npred_s[pl] = (float)s;
        }
        __syncthreads();

        // iou_pc[pl][c] = sum_b O/(n_pred + n_tgt - O); gNT reads are L1-hot
        for (int idx = tid; idx < 4 * NC; idx += 256) {
            int pl = idx / NC, cls = idx - pl * NC;
            float np = npred_s[pl];
            float acc = 0.f;
            #pragma unroll
            for (int b = 0; b < B_; ++b) {
                int lk = pl * T_ + b * NC + cls;
                u32 w = hist[lk >> 1];
                u32 v = (lk & 1) ? (w >> 16) : (w & 0xFFFFu);
                if (v) {
                    float fv = (float)v;
                    acc += fv * __builtin_amdgcn_rcpf(np + (float)gNT[b * NC + cls] - fv);
                }
            }
            iou_pc[pl][cls] = acc;
        }
        __syncthreads();

        // matmul with targets (each element read once for all 4 rows)
        float o0 = 0.f, o1 = 0.f, o2 = 0.f, o3 = 0.f;
        if (tid < NC) {
            for (int k = 0; k < NC; ++k) {
                float tv = targets[k * NC + tid];
                o0 += iou_pc[0][k] * tv;
                o1 += iou_pc[1][k] * tv;
                o2 += iou_pc[2][k] * tv;
                o3 += iou_pc[3][k] * tv;
            }
        }

        // single float4 tree reduction for the 4 denominators
        red4[tid] = (tid < NC) ? make_float4(o0, o1, o2, o3)
                               : make_float4(0.f, 0.f, 0.f, 0.f);
        __syncthreads();
        for (int o = 128; o > 0; o >>= 1) {
            if (tid < o) {
                float4 a = red4[tid], b = red4[tid + o];
                red4[tid] = make_float4(a.x + b.x, a.y + b.y, a.z + b.z, a.w + b.w);
            }
            __syncthreads();
        }
        float4 den = red4[0];

        if (tid < NC) {
            size_t ob = (size_t)(bkt * 16 + q * 4) * NC + tid;
            out[ob + 0 * NC] = o0 * __builtin_amdgcn_rcpf(den.x);
            out[ob + 1 * NC] = o1 * __builtin_amdgcn_rcpf(den.y);
            out[ob + 2 * NC] = o2 * __builtin_amdgcn_rcpf(den.z);
            out[ob + 3 * NC] = o3 * __builtin_amdgcn_rcpf(den.w);
        }
    }
}

// ---------------------------------------------------------------------------
extern "C" void kernel_launch(void* const* d_in, const int* in_sizes, int n_in,
                              void* d_out, int out_size, void* d_ws, size_t ws_size,
                              hipStream_t stream) {
    const int*   pred    = (const int*)d_in[0];
    const int*   tgt     = (const int*)d_in[1];
    const float* targets = (const float*)d_in[2];
    float*       out     = (float*)d_out;

    u32* gCount  = (u32*)d_ws;                          // 256
    u32* gNT     = gCount + PBKT;                       // 2400
    u16* records = (u16*)(gNT + T_);                    // 256*18432 u16 = 9.4 MB

    void* kargs[] = {(void*)&pred, (void*)&tgt, (void*)&records, (void*)&gCount,
                     (void*)&gNT, (void*)&targets, (void*)&out};
    hipLaunchCooperativeKernel((const void*)fused_kernel, dim3(GRID), dim3(256),
                               kargs, 0, stream);
}

// Round 9
// 62.023 us; speedup vs baseline: 5.2982x; 5.2982x over previous
//
#include <hip/hip_runtime.h>

// Problem constants (fixed by setup_inputs)
#define B_    16
#define N_    262144            // 2^18 pixels per image
#define NC    150               // classes
#define NP    4096              // pred segment ids
#define T_    (B_ * NC)         // 2400 distinct target ids
#define TOTAL (B_ * N_)         // 4,194,304 pixels

// partition: 256 parent buckets (pred>>4)
#define PBKT       256
#define PCAP       18432        // mean 16384, +16 sigma
#define KEY_SHIFT  16           // local key = (p&15)*2400 + t < 38400 < 2^16
#define P1_BLOCKS  1024
#define P1_PIX     (TOTAL / P1_BLOCKS)   // 4096 pixels per block (one image)
#define P1_PER_THR (P1_PIX / 256)        // 16 per thread

// iou: 4 co-blocks per parent bucket, each owns 4 pred rows
#define QT         9600         // local keys per quadrant (4*2400)

// gCount padded: one counter per 256 B (own L2 line/channel) to kill
// atomic serialization (262K atomics over 16 packed lines was ~tens of us)
#define CSTRIDE    64                      // u32 stride between counters
#define NCOUNTERS  (PBKT * CSTRIDE + T_)   // 16384 + 2400 = 18784 u32

typedef unsigned int u32;
typedef unsigned short u16;

// ---------------------------------------------------------------------------
// Kernel 0: zero the counters (padded gCount + gNT)
// ---------------------------------------------------------------------------
__global__ __launch_bounds__(256) void init_kernel(u32* __restrict__ ctrs) {
    int i = blockIdx.x * 256 + threadIdx.x;
    if (i < NCOUNTERS) ctrs[i] = 0;
}

// ---------------------------------------------------------------------------
// Kernel 1: radix-split pixels into 256 parent buckets (+ fused n_tgt).
// Record = u16 localkey = (p&15)*2400 + (b*150 + cls).
// ---------------------------------------------------------------------------
__global__ __launch_bounds__(256) void partition_kernel(const int* __restrict__ pred,
                                                        const int* __restrict__ tgt,
                                                        u16* __restrict__ records,
                                                        u32* __restrict__ gCount,
                                                        u32* __restrict__ gNT) {
    __shared__ u32 cnt[PBKT];
    __shared__ u32 lstart[PBKT];
    __shared__ u32 goff[PBKT];       // gbase - lstart
    __shared__ u32 cursor[PBKT];
    __shared__ u32 nth[NC];
    __shared__ u32 wsum[4];
    __shared__ u32 staging[P1_PIX];  // 16 KB

    int tid = threadIdx.x;
    cnt[tid] = 0;
    if (tid < NC) nth[tid] = 0;
    __syncthreads();

    u32 keys[P1_PER_THR];
    int base = blockIdx.x * P1_PIX;
    int b_img = base >> 18;                  // constant per block
    const int4* pred4 = (const int4*)pred;
    const int4* tgt4  = (const int4*)tgt;

    #pragma unroll
    for (int k = 0; k < P1_PER_THR / 4; ++k) {
        int vi = (base >> 2) + k * 256 + tid;
        int4 pv = pred4[vi];
        int4 tv = tgt4[vi];
        int pe[4] = {pv.x, pv.y, pv.z, pv.w};
        int te[4] = {tv.x, tv.y, tv.z, tv.w};
        #pragma unroll
        for (int e = 0; e < 4; ++e) {
            int p = pe[e];
            u32 bkt = (u32)(p >> 4);
            u32 lk  = (u32)((p & 15) * T_ + b_img * NC + te[e]);
            keys[k * 4 + e] = (bkt << KEY_SHIFT) | lk;
            atomicAdd(&cnt[bkt], 1u);
            atomicAdd(&nth[te[e]], 1u);
        }
    }
    __syncthreads();

    // exclusive scan over 256 bucket counts: wave shfl scan + 1 barrier
    {
        u32 myc = cnt[tid];
        u32 v = myc;
        #pragma unroll
        for (int o = 1; o < 64; o <<= 1) {
            u32 t = __shfl_up(v, o);
            if ((tid & 63) >= o) v += t;
        }
        if ((tid & 63) == 63) wsum[tid >> 6] = v;
        __syncthreads();
        u32 woff = 0;
        #pragma unroll
        for (int w = 0; w < 3; ++w) woff += (w < (tid >> 6)) ? wsum[w] : 0;
        u32 ex = v + woff - myc;                 // exclusive prefix
        lstart[tid] = ex;
        cursor[tid] = ex;
        u32 gb = atomicAdd(&gCount[tid * CSTRIDE], myc);
        goff[tid] = gb - ex;
    }
    if (tid < NC && nth[tid]) atomicAdd(&gNT[b_img * NC + tid], nth[tid]);
    __syncthreads();

    // scatter into LDS staging, sorted by bucket
    #pragma unroll
    for (int k = 0; k < P1_PER_THR; ++k) {
        u32 v = keys[k];
        u32 pos = atomicAdd(&cursor[v >> KEY_SHIFT], 1u);
        staging[pos] = v;
    }
    __syncthreads();

    // coalesced flush: ~16-record (32 B) runs per bucket
    for (int r = tid; r < P1_PIX; r += 256) {
        u32 v = staging[r];
        u32 bkt = v >> KEY_SHIFT;
        u32 gp = goff[bkt] + (u32)r;         // = gbase + (r - lstart)
        if (gp < PCAP) records[(size_t)bkt * PCAP + gp] = (u16)(v & 0xFFFFu);
    }
}

// ---------------------------------------------------------------------------
// Kernel 2: 4 co-blocks per parent bucket, each owning 4 pred rows.
// Scans the bucket's records (L2/L3-hot), filters with one compare.
// ---------------------------------------------------------------------------
__global__ __launch_bounds__(256, 6) void iou_kernel(const u16* __restrict__ records,
                                                     const u32* __restrict__ gCount,
                                                     const u32* __restrict__ gNT,
                                                     const float* __restrict__ targets,
                                                     float* __restrict__ out) {
    __shared__ u32 hist[QT / 2];              // 4800 words = 19.2 KB
    __shared__ float npred_s[4];
    __shared__ float iou_pc[4][NC];           // 2.4 KB
    __shared__ float4 red4[256];              // 4 KB

    int tid = threadIdx.x;
    int bkt = blockIdx.x >> 2;
    int q   = blockIdx.x & 3;
    u32 lo = (u32)(q * QT);

    // vectorized hist zero
    {
        uint4 z4 = make_uint4(0u, 0u, 0u, 0u);
        uint4* h4 = (uint4*)hist;
        for (int j = tid; j < QT / 8; j += 256) h4[j] = z4;
    }
    __syncthreads();

    u32 cnt = gCount[bkt * CSTRIDE];
    if (cnt > PCAP) cnt = PCAP;
    const u16* rec = records + (size_t)bkt * PCAP;

    // vectorized scan (8 B/lane), single-compare filter to this quadrant
    u32 nv4 = cnt >> 2;
    const ushort4* rec4 = (const ushort4*)rec;
    for (u32 r = tid; r < nv4; r += 256) {
        ushort4 v4 = rec4[r];
        u32 e[4] = {v4.x, v4.y, v4.z, v4.w};
        #pragma unroll
        for (int i = 0; i < 4; ++i) {
            u32 lk = e[i] - lo;
            if (lk < (u32)QT)
                atomicAdd(&hist[lk >> 1], (lk & 1u) ? 65536u : 1u);
        }
    }
    for (u32 r = (nv4 << 2) + tid; r < cnt; r += 256) {
        u32 lk = (u32)rec[r] - lo;
        if (lk < (u32)QT)
            atomicAdd(&hist[lk >> 1], (lk & 1u) ? 65536u : 1u);
    }
    __syncthreads();

    // n_pred row sums: 4 waves, one pred row each (1200 words)
    {
        int pl = tid >> 6, lane = tid & 63;
        u32 s = 0;
        for (int w = lane; w < T_ / 2; w += 64) {
            u32 v = hist[pl * (T_ / 2) + w];
            s += (v & 0xFFFFu) + (v >> 16);
        }
        #pragma unroll
        for (int o = 32; o > 0; o >>= 1) s += __shfl_xor(s, o);
        if (lane == 0) npred_s[pl] = (float)s;
    }
    __syncthreads();

    // iou_pc[pl][c] = sum_b O/(n_pred + n_tgt - O); gNT reads are L1-hot
    for (int idx = tid; idx < 4 * NC; idx += 256) {
        int pl = idx / NC, cls = idx - pl * NC;
        float np = npred_s[pl];
        float acc = 0.f;
        #pragma unroll
        for (int b = 0; b < B_; ++b) {
            int lk = pl * T_ + b * NC + cls;
            u32 w = hist[lk >> 1];
            u32 v = (lk & 1) ? (w >> 16) : (w & 0xFFFFu);
            if (v) {
                float fv = (float)v;
                acc += fv * __builtin_amdgcn_rcpf(np + (float)gNT[b * NC + cls] - fv);
            }
        }
        iou_pc[pl][cls] = acc;
    }
    __syncthreads();

    // matmul with targets (each element read once for all 4 rows)
    float o0 = 0.f, o1 = 0.f, o2 = 0.f, o3 = 0.f;
    if (tid < NC) {
        for (int k = 0; k < NC; ++k) {
            float tv = targets[k * NC + tid];
            o0 += iou_pc[0][k] * tv;
            o1 += iou_pc[1][k] * tv;
            o2 += iou_pc[2][k] * tv;
            o3 += iou_pc[3][k] * tv;
        }
    }

    // single float4 tree reduction for the 4 denominators
    red4[tid] = (tid < NC) ? make_float4(o0, o1, o2, o3)
                           : make_float4(0.f, 0.f, 0.f, 0.f);
    __syncthreads();
    for (int o = 128; o > 0; o >>= 1) {
        if (tid < o) {
            float4 a = red4[tid], b = red4[tid + o];
            red4[tid] = make_float4(a.x + b.x, a.y + b.y, a.z + b.z, a.w + b.w);
        }
        __syncthreads();
    }
    float4 den = red4[0];

    if (tid < NC) {
        size_t ob = (size_t)(bkt * 16 + q * 4) * NC + tid;
        out[ob + 0 * NC] = o0 * __builtin_amdgcn_rcpf(den.x);
        out[ob + 1 * NC] = o1 * __builtin_amdgcn_rcpf(den.y);
        out[ob + 2 * NC] = o2 * __builtin_amdgcn_rcpf(den.z);
        out[ob + 3 * NC] = o3 * __builtin_amdgcn_rcpf(den.w);
    }
}

// ---------------------------------------------------------------------------
extern "C" void kernel_launch(void* const* d_in, const int* in_sizes, int n_in,
                              void* d_out, int out_size, void* d_ws, size_t ws_size,
                              hipStream_t stream) {
    const int*   pred    = (const int*)d_in[0];
    const int*   tgt     = (const int*)d_in[1];
    const float* targets = (const float*)d_in[2];
    float*       out     = (float*)d_out;

    u32* gCount  = (u32*)d_ws;                          // 256 * CSTRIDE (64 KB)
    u32* gNT     = gCount + PBKT * CSTRIDE;             // 2400
    u16* records = (u16*)(gNT + T_);                    // 256*18432 u16 = 9.4 MB

    init_kernel<<<(NCOUNTERS + 255) / 256, 256, 0, stream>>>((u32*)d_ws);
    partition_kernel<<<P1_BLOCKS, 256, 0, stream>>>(pred, tgt, records, gCount, gNT);
    iou_kernel<<<PBKT * 4, 256, 0, stream>>>(records, gCount, gNT, targets, out);
}

// Round 10
// 60.238 us; speedup vs baseline: 5.4552x; 1.0296x over previous
//
#include <hip/hip_runtime.h>

// Problem constants (fixed by setup_inputs)
#define B_    16
#define N_    262144            // 2^18 pixels per image
#define NC    150               // classes
#define NP    4096              // pred segment ids
#define T_    (B_ * NC)         // 2400 distinct target ids
#define TOTAL (B_ * N_)         // 4,194,304 pixels

// partition: 256 parent buckets (pred>>4)
#define PBKT       256
#define PCAP       18432        // mean 16384, +16 sigma
#define KEY_SHIFT  16           // local key = (p&15)*2400 + t < 38400 < 2^16
#define P1_BLOCKS  1024
#define P1_PIX     (TOTAL / P1_BLOCKS)   // 4096 pixels per block (one image)
#define P1_PER_THR (P1_PIX / 256)        // 16 per thread

// iou: 4 co-blocks per parent bucket, each owns 4 pred rows
#define QT         9600         // local keys per quadrant (4*2400)

// gCount padded: one counter per 256 B (own L2 line) -> no atomic serialization
#define CSTRIDE    64
#define NCOUNTERS  (PBKT * CSTRIDE + T_)   // 16384 + 2400 = 18784 u32

typedef unsigned int u32;
typedef unsigned short u16;

// ---------------------------------------------------------------------------
// Kernel 0: zero the counters (padded gCount + gNT)
// ---------------------------------------------------------------------------
__global__ __launch_bounds__(256) void init_kernel(u32* __restrict__ ctrs) {
    int i = blockIdx.x * 256 + threadIdx.x;
    if (i < NCOUNTERS) ctrs[i] = 0;
}

// ---------------------------------------------------------------------------
// Kernel 1: radix-split pixels into 256 parent buckets (+ fused n_tgt).
// Record = u16 localkey = (p&15)*2400 + (b*150 + cls).
// ---------------------------------------------------------------------------
__global__ __launch_bounds__(256) void partition_kernel(const int* __restrict__ pred,
                                                        const int* __restrict__ tgt,
                                                        u16* __restrict__ records,
                                                        u32* __restrict__ gCount,
                                                        u32* __restrict__ gNT) {
    __shared__ u32 cnt[PBKT];
    __shared__ u32 lstart[PBKT];
    __shared__ u32 goff[PBKT];       // gbase - lstart
    __shared__ u32 cursor[PBKT];
    __shared__ u32 nth[NC];
    __shared__ u32 wsum[4];
    __shared__ u32 staging[P1_PIX];  // 16 KB

    int tid = threadIdx.x;
    cnt[tid] = 0;
    if (tid < NC) nth[tid] = 0;

    // hoist ALL global loads first: 8 independent int4 loads in flight
    int base = blockIdx.x * P1_PIX;
    int b_img = base >> 18;                  // constant per block
    const int4* pred4 = (const int4*)pred;
    const int4* tgt4  = (const int4*)tgt;
    int4 pv[4], tv[4];
    #pragma unroll
    for (int k = 0; k < 4; ++k) {
        int vi = (base >> 2) + k * 256 + tid;
        pv[k] = pred4[vi];
        tv[k] = tgt4[vi];
    }
    __syncthreads();

    u32 keys[P1_PER_THR];
    #pragma unroll
    for (int k = 0; k < 4; ++k) {
        int pe[4] = {pv[k].x, pv[k].y, pv[k].z, pv[k].w};
        int te[4] = {tv[k].x, tv[k].y, tv[k].z, tv[k].w};
        #pragma unroll
        for (int e = 0; e < 4; ++e) {
            int p = pe[e];
            u32 bkt = (u32)(p >> 4);
            u32 lk  = (u32)((p & 15) * T_ + b_img * NC + te[e]);
            keys[k * 4 + e] = (bkt << KEY_SHIFT) | lk;
            atomicAdd(&cnt[bkt], 1u);
            atomicAdd(&nth[te[e]], 1u);
        }
    }
    __syncthreads();

    // exclusive scan over 256 bucket counts: wave shfl scan + 1 barrier
    {
        u32 myc = cnt[tid];
        u32 v = myc;
        #pragma unroll
        for (int o = 1; o < 64; o <<= 1) {
            u32 t = __shfl_up(v, o);
            if ((tid & 63) >= o) v += t;
        }
        if ((tid & 63) == 63) wsum[tid >> 6] = v;
        __syncthreads();
        u32 woff = 0;
        #pragma unroll
        for (int w = 0; w < 3; ++w) woff += (w < (tid >> 6)) ? wsum[w] : 0;
        u32 ex = v + woff - myc;                 // exclusive prefix
        lstart[tid] = ex;
        cursor[tid] = ex;
        u32 gb = atomicAdd(&gCount[tid * CSTRIDE], myc);
        goff[tid] = gb - ex;
    }
    if (tid < NC && nth[tid]) atomicAdd(&gNT[b_img * NC + tid], nth[tid]);
    __syncthreads();

    // scatter into LDS staging, sorted by bucket
    #pragma unroll
    for (int k = 0; k < P1_PER_THR; ++k) {
        u32 v = keys[k];
        u32 pos = atomicAdd(&cursor[v >> KEY_SHIFT], 1u);
        staging[pos] = v;
    }
    __syncthreads();

    // coalesced flush: ~16-record (32 B) runs per bucket
    for (int r = tid; r < P1_PIX; r += 256) {
        u32 v = staging[r];
        u32 bkt = v >> KEY_SHIFT;
        u32 gp = goff[bkt] + (u32)r;         // = gbase + (r - lstart)
        if (gp < PCAP) records[(size_t)bkt * PCAP + gp] = (u16)(v & 0xFFFFu);
    }
}

// ---------------------------------------------------------------------------
// Kernel 2: 4 co-blocks per parent bucket, each owning 4 pred rows.
// XCD co-location: bkt = blockIdx&255 so co-blocks {b,256+b,512+b,768+b}
// are all == b (mod 8) -> same XCD -> bucket slice read once from L3,
// then L2-hit for the other three. 32 buckets/XCD = 1.2 MB << 4 MB L2.
// ---------------------------------------------------------------------------
__global__ __launch_bounds__(256, 6) void iou_kernel(const u16* __restrict__ records,
                                                     const u32* __restrict__ gCount,
                                                     const u32* __restrict__ gNT,
                                                     const float* __restrict__ targets,
                                                     float* __restrict__ out) {
    __shared__ u32 hist[QT / 2];              // 4800 words = 19.2 KB
    __shared__ float npred_s[4];
    __shared__ float iou_pc[4][NC];           // 2.4 KB
    __shared__ float4 red4[256];              // 4 KB

    int tid = threadIdx.x;
    int bkt = blockIdx.x & 255;               // XCD co-location swizzle
    int q   = blockIdx.x >> 8;
    u32 lo = (u32)(q * QT);

    // vectorized hist zero
    {
        uint4 z4 = make_uint4(0u, 0u, 0u, 0u);
        uint4* h4 = (uint4*)hist;
        for (int j = tid; j < QT / 8; j += 256) h4[j] = z4;
    }
    __syncthreads();

    u32 cnt = gCount[bkt * CSTRIDE];
    if (cnt > PCAP) cnt = PCAP;
    const u16* rec = records + (size_t)bkt * PCAP;

    // vectorized scan (8 B/lane) with manual 1-deep prefetch,
    // single-compare filter to this quadrant
    u32 nv4 = cnt >> 2;
    const ushort4* rec4 = (const ushort4*)rec;
    {
        u32 r = tid;
        ushort4 cur;
        if (r < nv4) cur = rec4[r];
        for (; r < nv4; ) {
            u32 rn = r + 256;
            ushort4 nxt;
            if (rn < nv4) nxt = rec4[rn];
            u32 e[4] = {cur.x, cur.y, cur.z, cur.w};
            #pragma unroll
            for (int i = 0; i < 4; ++i) {
                u32 lk = e[i] - lo;
                if (lk < (u32)QT)
                    atomicAdd(&hist[lk >> 1], (lk & 1u) ? 65536u : 1u);
            }
            cur = nxt;
            r = rn;
        }
    }
    for (u32 r = (nv4 << 2) + tid; r < cnt; r += 256) {
        u32 lk = (u32)rec[r] - lo;
        if (lk < (u32)QT)
            atomicAdd(&hist[lk >> 1], (lk & 1u) ? 65536u : 1u);
    }
    __syncthreads();

    // n_pred row sums: 4 waves, one pred row each (1200 words)
    {
        int pl = tid >> 6, lane = tid & 63;
        u32 s = 0;
        for (int w = lane; w < T_ / 2; w += 64) {
            u32 v = hist[pl * (T_ / 2) + w];
            s += (v & 0xFFFFu) + (v >> 16);
        }
        #pragma unroll
        for (int o = 32; o > 0; o >>= 1) s += __shfl_xor(s, o);
        if (lane == 0) npred_s[pl] = (float)s;
    }
    __syncthreads();

    // iou_pc[pl][c] = sum_b O/(n_pred + n_tgt - O); gNT reads are L1-hot
    for (int idx = tid; idx < 4 * NC; idx += 256) {
        int pl = idx / NC, cls = idx - pl * NC;
        float np = npred_s[pl];
        float acc = 0.f;
        #pragma unroll
        for (int b = 0; b < B_; ++b) {
            int lk = pl * T_ + b * NC + cls;
            u32 w = hist[lk >> 1];
            u32 v = (lk & 1) ? (w >> 16) : (w & 0xFFFFu);
            if (v) {
                float fv = (float)v;
                acc += fv * __builtin_amdgcn_rcpf(np + (float)gNT[b * NC + cls] - fv);
            }
        }
        iou_pc[pl][cls] = acc;
    }
    __syncthreads();

    // matmul with targets (each element read once for all 4 rows)
    float o0 = 0.f, o1 = 0.f, o2 = 0.f, o3 = 0.f;
    if (tid < NC) {
        for (int k = 0; k < NC; ++k) {
            float tv = targets[k * NC + tid];
            o0 += iou_pc[0][k] * tv;
            o1 += iou_pc[1][k] * tv;
            o2 += iou_pc[2][k] * tv;
            o3 += iou_pc[3][k] * tv;
        }
    }

    // single float4 tree reduction for the 4 denominators
    red4[tid] = (tid < NC) ? make_float4(o0, o1, o2, o3)
                           : make_float4(0.f, 0.f, 0.f, 0.f);
    __syncthreads();
    for (int o = 128; o > 0; o >>= 1) {
        if (tid < o) {
            float4 a = red4[tid], b = red4[tid + o];
            red4[tid] = make_float4(a.x + b.x, a.y + b.y, a.z + b.z, a.w + b.w);
        }
        __syncthreads();
    }
    float4 den = red4[0];

    if (tid < NC) {
        size_t ob = (size_t)(bkt * 16 + q * 4) * NC + tid;
        out[ob + 0 * NC] = o0 * __builtin_amdgcn_rcpf(den.x);
        out[ob + 1 * NC] = o1 * __builtin_amdgcn_rcpf(den.y);
        out[ob + 2 * NC] = o2 * __builtin_amdgcn_rcpf(den.z);
        out[ob + 3 * NC] = o3 * __builtin_amdgcn_rcpf(den.w);
    }
}

// ---------------------------------------------------------------------------
extern "C" void kernel_launch(void* const* d_in, const int* in_sizes, int n_in,
                              void* d_out, int out_size, void* d_ws, size_t ws_size,
                              hipStream_t stream) {
    const int*   pred    = (const int*)d_in[0];
    const int*   tgt     = (const int*)d_in[1];
    const float* targets = (const float*)d_in[2];
    float*       out     = (float*)d_out;

    u32* gCount  = (u32*)d_ws;                          // 256 * CSTRIDE (64 KB)
    u32* gNT     = gCount + PBKT * CSTRIDE;             // 2400
    u16* records = (u16*)(gNT + T_);                    // 256*18432 u16 = 9.4 MB

    init_kernel<<<(NCOUNTERS + 255) / 256, 256, 0, stream>>>((u32*)d_ws);
    partition_kernel<<<P1_BLOCKS, 256, 0, stream>>>(pred, tgt, records, gCount, gNT);
    iou_kernel<<<PBKT * 4, 256, 0, stream>>>(records, gCount, gNT, targets, out);
}